// Round 1
// baseline (3962.456 us; speedup 1.0000x reference)
//
#include <hip/hip_runtime.h>

#define BATCH 512
#define SEQ   128
#define EMBED 300
#define UNITS 512

typedef short  short8   __attribute__((ext_vector_type(8)));
typedef float  floatx16 __attribute__((ext_vector_type(16)));

#define KX   304   // padded x-K (19*16)
#define KXF  19
#define KHF  32

// LDS layout (dynamic)
#define SH_H   0         // 64 rows * 1024B (bf16 x 512, XOR-swizzled blocks)
#define SH_X   65536     // 64 rows * 608B
#define SH_B2  104448    // 2 colfrags * 19 kfrags * 1024B
#define SMEM_BYTES 143360

// ws layout
#define WS_CNT   0
#define WS_HBUF  4096                    // 2 * 512KB
#define WS_XBUF  (4096 + 1048576)        // 2 * 8 * 38912
#define WS_NEED  (WS_XBUF + 2*8*38912)

__device__ __forceinline__ unsigned short f2bf(float f) {
  union { float f; unsigned u; } v; v.f = f;
  unsigned r = v.u + 0x7fff + ((v.u >> 16) & 1);
  return (unsigned short)(r >> 16);
}
__device__ __forceinline__ float sigm(float x) { return 1.f / (1.f + __expf(-x)); }
__device__ __forceinline__ float tanh_f(float x) {
  float e = __expf(2.f * x);
  return 1.f - 2.f / (e + 1.f);
}

__device__ __forceinline__ void async_copy16(const char* g, char* l) {
  __builtin_amdgcn_global_load_lds(
      (const __attribute__((address_space(1))) unsigned int*)g,
      (__attribute__((address_space(3))) unsigned int*)l, 16, 0, 0);
}

// barrier among the 32 WGs of one row-block (monotonic counter, no reset)
__device__ __forceinline__ void group_barrier(unsigned* cnt, unsigned target) {
  __syncthreads();                       // all wg stores issued+drained (vmcnt0 before s_barrier)
  if (threadIdx.x == 0) {
    __threadfence();                     // agent release: L2 writeback (cross-XCD visibility)
    __hip_atomic_fetch_add(cnt, 1u, __ATOMIC_RELAXED, __HIP_MEMORY_SCOPE_AGENT);
    while (__hip_atomic_load(cnt, __ATOMIC_RELAXED, __HIP_MEMORY_SCOPE_AGENT) < target)
      __builtin_amdgcn_s_sleep(2);
    __threadfence();                     // agent acquire: invalidate stale L1/L2
  }
  __syncthreads();
}

extern "C" __global__ void __launch_bounds__(128, 1)
lstm_enc(const int* __restrict__ seq, const float* __restrict__ h0,
         const float* __restrict__ c0, const float* __restrict__ emb,
         const float* __restrict__ kern, const float* __restrict__ rkern,
         const float* __restrict__ bias, float* __restrict__ out,
         char* __restrict__ ws)
{
  extern __shared__ __align__(16) char smem[];
  char* sh_h  = smem + SH_H;
  char* sh_x  = smem + SH_X;
  char* sh_b2 = smem + SH_B2;

  const int tid  = threadIdx.x;
  const int lane = tid & 63;
  const int w    = tid >> 6;          // wave id: row strip w*32..w*32+31
  const int rb   = blockIdx.x & 7;    // row block (group; maps to one XCD)
  const int ug   = blockIdx.x >> 3;   // unit block 0..31

  unsigned* cnt = (unsigned*)(ws + WS_CNT) + rb;
  char* hb0 = ws + WS_HBUF;
  char* hb1 = ws + WS_HBUF + 524288;
  char* xt0 = ws + WS_XBUF + (0 * 8 + rb) * 38912;
  char* xt1 = ws + WS_XBUF + (1 * 8 + rb) * 38912;

  const int  n    = lane & 31;        // frag col
  const int  half = lane >> 5;        // k-half
  const int  u    = ug * 16 + (n & 15);
  const bool lo   = (n < 16);

  // column mapping: colfrag0 = [i|f] x 16 units, colfrag1 = [g|o] x 16 units
  const int gcol0 = (lo ? 0    : 512 ) + (n & 15) + ug * 16;
  const int gcol1 = (lo ? 1024 : 1536) + (n & 15) + ug * 16;

  // ---- rec_kernel B-frags -> registers (step-invariant) ----
  short8 b1[2][KHF];
#pragma unroll
  for (int kf = 0; kf < KHF; ++kf) {
    int k0 = kf * 16 + half * 8;
    short8 p0, p1;
#pragma unroll
    for (int j = 0; j < 8; ++j) {
      p0[j] = (short)f2bf(rkern[(k0 + j) * 2048 + gcol0]);
      p1[j] = (short)f2bf(rkern[(k0 + j) * 2048 + gcol1]);
    }
    b1[0][kf] = p0; b1[1][kf] = p1;
  }
  // ---- kernel (x-weights) B-frags -> LDS (step-invariant) ----
#pragma unroll
  for (int kf = 0; kf < KXF; ++kf) {
    int k0 = kf * 16 + half * 8;
    short8 p0, p1;
#pragma unroll
    for (int j = 0; j < 8; ++j) {
      int k = k0 + j;
      p0[j] = (short)((k < EMBED) ? f2bf(kern[k * 2048 + gcol0]) : 0);
      p1[j] = (short)((k < EMBED) ? f2bf(kern[k * 2048 + gcol1]) : 0);
    }
    *(short8*)(sh_b2 + ((0 * KXF + kf) * 64 + lane) * 16) = p0;
    *(short8*)(sh_b2 + ((1 * KXF + kf) * 64 + lane) * 16) = p1;
  }

  const float bsi = bias[u], bsf = bias[512 + u], bsg = bias[1024 + u], bso = bias[1536 + u];

  // ---- init h/c state regs; write h0 (bf16, swizzled) into hbuf[1] ----
  float hreg[16], creg[16];
#pragma unroll
  for (int r = 0; r < 16; ++r) {
    int rowl   = (r & 3) + 8 * (r >> 2) + 4 * half;
    int brow   = rb * 64 + w * 32 + rowl;
    float hv = h0[brow * 512 + u];
    float cv = c0[brow * 512 + u];
    hreg[r] = hv; creg[r] = cv;
    if (lo) {
      int blk = (((u >> 3) ^ rowl) * 16) + (u & 7) * 2;
      *(unsigned short*)(hb1 + brow * 1024 + blk) = f2bf(hv);
    }
  }

  // ---- gather x for t=0 (this WG owns rows 2*ug, 2*ug+1 of its row block) ----
  {
    int r0 = rb * 64 + 2 * ug;
    for (int r = 0; r < 2; ++r) {
      int tok = seq[(r0 + r) * SEQ + 0];
      for (int k = tid; k < KX; k += 128) {
        unsigned short v = (k < EMBED) ? f2bf(emb[tok * EMBED + k]) : (unsigned short)0;
        *(unsigned short*)(xt0 + (2 * ug + r) * 608 + k * 2) = v;
      }
    }
  }

  unsigned bar_target = 32;
  group_barrier(cnt, bar_target);

#pragma unroll 1
  for (int t = 0; t < SEQ; ++t) {
    const char* hsrc_base = ((t & 1) ? hb0 : hb1);   // read hbuf[(t+1)&1]
    char*       hdst_base = ((t & 1) ? hb1 : hb0);   // write hbuf[t&1]
    const char* xsrc_base = ((t & 1) ? xt1 : xt0);
    char*       xnxt_base = ((t & 1) ? xt0 : xt1);

    // stage h tile rows [w*32, w*32+32)
    {
      const char* hs = hsrc_base + (rb * 64 + w * 32) * 1024;
      char*       hd = sh_h + (w * 32) * 1024;
#pragma unroll
      for (int i = 0; i < 32; ++i)
        async_copy16(hs + i * 1024 + lane * 16, hd + i * 1024);
    }
    // stage x tile (flat copy, wave halves)
    {
      const char* xs = xsrc_base + w * 19456;
      char*       xd = sh_x + w * 19456;
#pragma unroll
      for (int i = 0; i < 19; ++i)
        async_copy16(xs + i * 1024 + lane * 16, xd + i * 1024);
    }

    // pipelined gather of x for t+1
    if (t < SEQ - 1) {
      int r0 = rb * 64 + 2 * ug;
      for (int r = 0; r < 2; ++r) {
        int tok = seq[(r0 + r) * SEQ + (t + 1)];
        for (int k = tid; k < KX; k += 128) {
          unsigned short v = (k < EMBED) ? f2bf(emb[tok * EMBED + k]) : (unsigned short)0;
          *(unsigned short*)(xnxt_base + (2 * ug + r) * 608 + k * 2) = v;
        }
      }
    }

    __syncthreads();   // drains global_load_lds + orders LDS

    floatx16 acc0, acc1;
#pragma unroll
    for (int i = 0; i < 16; ++i) { acc0[i] = 0.f; acc1[i] = 0.f; }

    // K-loop: recurrent part (B from registers, A from swizzled LDS)
#pragma unroll
    for (int kf = 0; kf < KHF; ++kf) {
      int blk = (kf * 2 + half) ^ n;
      short8 a = *(const short8*)(sh_h + (w * 32 + n) * 1024 + blk * 16);
      acc0 = __builtin_amdgcn_mfma_f32_32x32x16_bf16(a, b1[0][kf], acc0, 0, 0, 0);
      acc1 = __builtin_amdgcn_mfma_f32_32x32x16_bf16(a, b1[1][kf], acc1, 0, 0, 0);
    }
    // K-loop: input part (A from LDS x tile, B from LDS)
#pragma unroll
    for (int kf = 0; kf < KXF; ++kf) {
      short8 a  = *(const short8*)(sh_x + (w * 32 + n) * 608 + kf * 32 + half * 16);
      short8 p0 = *(const short8*)(sh_b2 + ((0 * KXF + kf) * 64 + lane) * 16);
      short8 p1 = *(const short8*)(sh_b2 + ((1 * KXF + kf) * 64 + lane) * 16);
      acc0 = __builtin_amdgcn_mfma_f32_32x32x16_bf16(a, p0, acc0, 0, 0, 0);
      acc1 = __builtin_amdgcn_mfma_f32_32x32x16_bf16(a, p1, acc1, 0, 0, 0);
    }

    // epilogue: gates, state update, mask, stores
#pragma unroll
    for (int r = 0; r < 16; ++r) {
      float a0 = acc0[r], a1 = acc1[r];
      float s0 = __shfl_xor(a0, 16, 64);
      float s1 = __shfl_xor(a1, 16, 64);
      float zi = (lo ? a0 : s0) + bsi;
      float zf = (lo ? s0 : a0) + bsf;
      float zg = (lo ? a1 : s1) + bsg;
      float zo = (lo ? s1 : a1) + bso;
      float iv = sigm(zi), fv = sigm(zf), gv = tanh_f(zg), ov = sigm(zo);
      float cn = fv * creg[r] + iv * gv;
      float hn = ov * tanh_f(cn);
      int rowl = (r & 3) + 8 * (r >> 2) + 4 * half;
      int brow = rb * 64 + w * 32 + rowl;
      int tok  = seq[brow * SEQ + t];
      if (tok == 0) { cn = creg[r]; hn = hreg[r]; }
      creg[r] = cn; hreg[r] = hn;
      if (lo) {
        out[brow * (SEQ * 512) + t * 512 + u] = hn;
        int blk = (((u >> 3) ^ rowl) * 16) + (u & 7) * 2;
        *(unsigned short*)(hdst_base + brow * 1024 + blk) = f2bf(hn);
        if (t == SEQ - 1) {
          out[BATCH * SEQ * 512 + brow * 512 + u] = hn;
          out[BATCH * SEQ * 512 + BATCH * 512 + brow * 512 + u] = cn;
        }
      }
    }

    if (t < SEQ - 1) { bar_target += 32; group_barrier(cnt, bar_target); }
  }
}

extern "C" void kernel_launch(void* const* d_in, const int* in_sizes, int n_in,
                              void* d_out, int out_size, void* d_ws, size_t ws_size,
                              hipStream_t stream) {
  if (ws_size < (size_t)WS_NEED) return;  // need ~1.6 MB scratch
  const int*   seq   = (const int*)d_in[0];
  const float* h0    = (const float*)d_in[1];
  const float* c0    = (const float*)d_in[2];
  const float* emb   = (const float*)d_in[3];
  const float* kern  = (const float*)d_in[4];
  const float* rkern = (const float*)d_in[5];
  const float* bias  = (const float*)d_in[6];
  float* out = (float*)d_out;

  hipFuncSetAttribute((const void*)lstm_enc,
                      hipFuncAttributeMaxDynamicSharedMemorySize, SMEM_BYTES);
  hipMemsetAsync(d_ws, 0, 4096, stream);  // zero barrier counters
  lstm_enc<<<dim3(256), dim3(128), SMEM_BYTES, stream>>>(
      seq, h0, c0, emb, kern, rkern, bias, out, (char*)d_ws);
}

// Round 2
// 2691.781 us; speedup vs baseline: 1.4721x; 1.4721x over previous
//
#include <hip/hip_runtime.h>

#define BATCH 512
#define SEQ   128
#define EMBED 300
#define UNITS 512

typedef short  short8   __attribute__((ext_vector_type(8)));
typedef float  floatx16 __attribute__((ext_vector_type(16)));

#define KXF  19    // x K-frags (304 = 19*16)
#define KHF  32    // h K-frags (512 = 32*16)

// LDS: weights only
#define SH_B1  0                     // h rec B cf1: 32 kf * 64 lanes * 16B = 32768
#define SH_B2  32768                 // x B frags: 2 cf * 19 kf * 1024B = 38912
#define SMEM_BYTES (32768 + 38912)   // 71680

// ws layout (fits the 1,675,264 B footprint already granted in R1)
#define WS_FLAGS 0                         // 8 groups * 32 WGs * 16B = 4096
#define WS_HBUF  4096                      // 2 buffers * 512 rows * 1024B (bf16, row-major)
#define WS_XBUF  (4096 + 1048576)          // 2 * 8 * 38912
#define WS_NEED  (WS_XBUF + 2 * 8 * 38912)

__device__ __forceinline__ unsigned short f2bf(float f) {
  union { float f; unsigned u; } v; v.f = f;
  unsigned r = v.u + 0x7fff + ((v.u >> 16) & 1);
  return (unsigned short)(r >> 16);
}
__device__ __forceinline__ float sigm(float x) { return 1.f / (1.f + __expf(-x)); }
__device__ __forceinline__ float tanh_f(float x) {
  float e = __expf(2.f * x);
  return 1.f - 2.f / (e + 1.f);
}

// coherent (LLC-level) exchange primitives — no cache-wide fences needed
__device__ __forceinline__ void g_store32(unsigned* p, unsigned v) {
  __hip_atomic_store(p, v, __ATOMIC_RELAXED, __HIP_MEMORY_SCOPE_AGENT);
}
__device__ __forceinline__ unsigned long long g_load64(const void* p) {
  return __hip_atomic_load((const unsigned long long*)p, __ATOMIC_RELAXED,
                           __HIP_MEMORY_SCOPE_AGENT);
}
__device__ __forceinline__ short8 ld_frag(const char* p) {
  union { unsigned long long q[2]; short8 s; } u;
  u.q[0] = g_load64(p);
  u.q[1] = g_load64(p + 8);
  return u.s;
}

// wait until all 32 flags of this group reach tgt (one load-round per poll)
__device__ __forceinline__ void poll_ge(const unsigned* gf, int lane, unsigned tgt) {
  const unsigned* p = gf + (lane & 31) * 4;   // 16B stride
  for (;;) {
    unsigned v = __hip_atomic_load(p, __ATOMIC_RELAXED, __HIP_MEMORY_SCOPE_AGENT);
    if (__ballot(v >= tgt) == ~0ull) break;
    __builtin_amdgcn_s_sleep(1);
  }
}

#define LDH_GRP(arr, base)                                         \
  do { _Pragma("unroll")                                           \
    for (int j = 0; j < 8; ++j) arr[j] = ld_frag(hrow + ((base) + j) * 32); \
  } while (0)

#define MFMA_H_GRP(arr, base)                                                     \
  do { _Pragma("unroll")                                                          \
    for (int j = 0; j < 8; ++j) {                                                 \
      const int kf = (base) + j;                                                  \
      acc0 = __builtin_amdgcn_mfma_f32_32x32x16_bf16(arr[j], b0[kf], acc0, 0,0,0);\
      short8 p1 = *(const short8*)(sh_b1 + (kf * 64 + lane) * 16);                \
      acc1 = __builtin_amdgcn_mfma_f32_32x32x16_bf16(arr[j], p1, acc1, 0,0,0);    \
    }                                                                             \
  } while (0)

extern "C" __global__ void __launch_bounds__(128, 1)
lstm_enc(const int* __restrict__ seq, const float* __restrict__ h0,
         const float* __restrict__ c0, const float* __restrict__ emb,
         const float* __restrict__ kern, const float* __restrict__ rkern,
         const float* __restrict__ bias, float* __restrict__ out,
         char* __restrict__ ws)
{
  extern __shared__ __align__(16) char smem[];
  char* sh_b1 = smem + SH_B1;
  char* sh_b2 = smem + SH_B2;

  const int tid  = threadIdx.x;
  const int lane = tid & 63;
  const int w    = tid >> 6;          // wave: rows w*32..w*32+31 of the 64-row block
  const int rb   = blockIdx.x & 7;    // row-block group
  const int ug   = blockIdx.x >> 3;   // unit block 0..31

  unsigned* gflags = (unsigned*)(ws + WS_FLAGS) + rb * 128;  // 32 flags * 16B
  unsigned* myflag = gflags + ug * 4;
  char* hb_[2] = { ws + WS_HBUF, ws + WS_HBUF + 524288 };
  char* xb_[2] = { ws + WS_XBUF + (0 * 8 + rb) * 38912,
                   ws + WS_XBUF + (1 * 8 + rb) * 38912 };

  const int  n    = lane & 31;
  const int  half = lane >> 5;
  const int  u    = ug * 16 + (n & 15);
  const bool lo   = (n < 16);

  const int gcol0 = (lo ? 0    : 512 ) + (n & 15) + ug * 16;  // [i|f]
  const int gcol1 = (lo ? 1024 : 1536) + (n & 15) + ug * 16;  // [g|o]

  // ---- rec_kernel B-frags: cf0 -> 128 VGPRs, cf1 -> LDS ----
  short8 b0[KHF];
#pragma unroll
  for (int kf = 0; kf < KHF; ++kf) {
    int k0 = kf * 16 + half * 8;
    short8 p0, p1;
#pragma unroll
    for (int j = 0; j < 8; ++j) {
      p0[j] = (short)f2bf(rkern[(k0 + j) * 2048 + gcol0]);
      p1[j] = (short)f2bf(rkern[(k0 + j) * 2048 + gcol1]);
    }
    b0[kf] = p0;
    *(short8*)(sh_b1 + (kf * 64 + lane) * 16) = p1;
  }
  // ---- x-weight B-frags -> LDS ----
#pragma unroll
  for (int kf = 0; kf < KXF; ++kf) {
    int k0 = kf * 16 + half * 8;
    short8 p0, p1;
#pragma unroll
    for (int j = 0; j < 8; ++j) {
      int k = k0 + j;
      p0[j] = (short)((k < EMBED) ? f2bf(kern[k * 2048 + gcol0]) : 0);
      p1[j] = (short)((k < EMBED) ? f2bf(kern[k * 2048 + gcol1]) : 0);
    }
    *(short8*)(sh_b2 + ((0 * KXF + kf) * 64 + lane) * 16) = p0;
    *(short8*)(sh_b2 + ((1 * KXF + kf) * 64 + lane) * 16) = p1;
  }

  const float bsi = bias[u], bsf = bias[512 + u], bsg = bias[1024 + u], bso = bias[1536 + u];

  // ---- init h/c; publish h(0) bf16 row-major into hb_[1] ----
  float hreg[16], creg[16];
#pragma unroll
  for (int r = 0; r < 16; ++r) {
    int rowl = (r & 3) + 8 * (r >> 2) + 4 * half;
    int brow = rb * 64 + w * 32 + rowl;
    float hv = h0[brow * 512 + u];
    float cv = c0[brow * 512 + u];
    hreg[r] = hv; creg[r] = cv;
    float hp = __shfl_xor(hv, 1, 64);
    if (lo && !(n & 1)) {
      unsigned d = (unsigned)f2bf(hv) | ((unsigned)f2bf(hp) << 16);
      g_store32((unsigned*)(hb_[1] + brow * 1024 + u * 2), d);
    }
  }

  // ---- gather x(0) into xb_[0] (WG owns group-local rows 2*ug, 2*ug+1) ----
  {
    int r0 = rb * 64 + 2 * ug;
#pragma unroll
    for (int r = 0; r < 2; ++r) {
      int tok = seq[(r0 + r) * SEQ + 0];
      const float* erow = emb + tok * EMBED;
      char* xd = xb_[0] + (2 * ug + r) * 608;
      for (int k2 = tid; k2 < 152; k2 += 128) {
        int k = 2 * k2;
        float e0 = (k     < EMBED) ? erow[k]     : 0.f;
        float e1 = (k + 1 < EMBED) ? erow[k + 1] : 0.f;
        unsigned d = (unsigned)f2bf(e0) | ((unsigned)f2bf(e1) << 16);
        g_store32((unsigned*)(xd + k2 * 4), d);
      }
    }
  }

  __syncthreads();                    // drains all vmcnt (per-wave) before flag
  if (tid == 0) g_store32(myflag, 1u);
  poll_ge(gflags, lane, 1u);

#pragma unroll 1
  for (int t = 0; t < SEQ; ++t) {
    const char* hsrc = hb_[(t + 1) & 1];
    char*       hdst = hb_[t & 1];
    const char* xsrc = xb_[t & 1];
    char*       xdst = xb_[(t + 1) & 1];

    // preload mask tokens (normal loads, issued before the atomic streams)
    int tok16[16];
#pragma unroll
    for (int r = 0; r < 16; ++r) {
      int rowl = (r & 3) + 8 * (r >> 2) + 4 * half;
      tok16[r] = seq[(rb * 64 + w * 32 + rowl) * SEQ + t];
    }

    // ---- issue x frags (19) + first 16 h frags; all pipelined 8B LLC loads ----
    const char* xrow = xsrc + (w * 32 + n) * 608 + half * 16;
    const char* hrow = hsrc + (rb * 64 + w * 32 + n) * 1024 + half * 16;
    short8 xf[KXF];
#pragma unroll
    for (int kf = 0; kf < KXF; ++kf) xf[kf] = ld_frag(xrow + kf * 32);
    short8 hA[8], hB[8];
    LDH_GRP(hA, 0);
    LDH_GRP(hB, 8);

    floatx16 acc0, acc1;
#pragma unroll
    for (int i = 0; i < 16; ++i) { acc0[i] = 0.f; acc1[i] = 0.f; }

    // x-part MFMA (h-load latency hides underneath)
#pragma unroll
    for (int kf = 0; kf < KXF; ++kf) {
      short8 p0 = *(const short8*)(sh_b2 + ((0 * KXF + kf) * 64 + lane) * 16);
      short8 p1 = *(const short8*)(sh_b2 + ((1 * KXF + kf) * 64 + lane) * 16);
      acc0 = __builtin_amdgcn_mfma_f32_32x32x16_bf16(xf[kf], p0, acc0, 0, 0, 0);
      acc1 = __builtin_amdgcn_mfma_f32_32x32x16_bf16(xf[kf], p1, acc1, 0, 0, 0);
    }
    // h-part MFMA, 4 groups of 8 kf, two alternating load windows
    MFMA_H_GRP(hA, 0);  LDH_GRP(hA, 16);
    MFMA_H_GRP(hB, 8);  LDH_GRP(hB, 24);
    MFMA_H_GRP(hA, 16);
    MFMA_H_GRP(hB, 24);

    // ---- epilogue: gates, state, mask, publish h(t+1) ----
#pragma unroll
    for (int r = 0; r < 16; ++r) {
      float a0 = acc0[r], a1 = acc1[r];
      float s0 = __shfl_xor(a0, 16, 64);
      float s1 = __shfl_xor(a1, 16, 64);
      float zi = (lo ? a0 : s0) + bsi;
      float zf = (lo ? s0 : a0) + bsf;
      float zg = (lo ? a1 : s1) + bsg;
      float zo = (lo ? s1 : a1) + bso;
      float iv = sigm(zi), fv = sigm(zf), gv = tanh_f(zg), ov = sigm(zo);
      float cn = fv * creg[r] + iv * gv;
      float hn = ov * tanh_f(cn);
      int rowl = (r & 3) + 8 * (r >> 2) + 4 * half;
      int brow = rb * 64 + w * 32 + rowl;
      if (tok16[r] == 0) { cn = creg[r]; hn = hreg[r]; }
      creg[r] = cn; hreg[r] = hn;
      float hp = __shfl_xor(hn, 1, 64);
      if (lo) {
        out[brow * (SEQ * 512) + t * 512 + u] = hn;
        if (!(n & 1)) {
          unsigned d = (unsigned)f2bf(hn) | ((unsigned)f2bf(hp) << 16);
          g_store32((unsigned*)(hdst + brow * 1024 + u * 2), d);
        }
        if (t == SEQ - 1) {
          out[BATCH * SEQ * 512 + brow * 512 + u] = hn;
          out[BATCH * SEQ * 512 + BATCH * 512 + brow * 512 + u] = cn;
        }
      }
    }

    // ---- gather x(t+1) one step ahead (pre-arrive: flag covers visibility) ----
    if (t < SEQ - 1) {
      int r0 = rb * 64 + 2 * ug;
#pragma unroll
      for (int r = 0; r < 2; ++r) {
        int tok = seq[(r0 + r) * SEQ + (t + 1)];
        const float* erow = emb + tok * EMBED;
        char* xd = xdst + (2 * ug + r) * 608;
        for (int k2 = tid; k2 < 152; k2 += 128) {
          int k = 2 * k2;
          float e0 = (k     < EMBED) ? erow[k]     : 0.f;
          float e1 = (k + 1 < EMBED) ? erow[k + 1] : 0.f;
          unsigned d = (unsigned)f2bf(e0) | ((unsigned)f2bf(e1) << 16);
          g_store32((unsigned*)(xd + k2 * 4), d);
        }
      }
      // arrive + wait (flag t+2)
      __syncthreads();                       // per-wave vmcnt(0) drain before flag
      if (tid == 0) g_store32(myflag, (unsigned)(t + 2));
      poll_ge(gflags, lane, (unsigned)(t + 2));
    }
  }
}

extern "C" void kernel_launch(void* const* d_in, const int* in_sizes, int n_in,
                              void* d_out, int out_size, void* d_ws, size_t ws_size,
                              hipStream_t stream) {
  if (ws_size < (size_t)WS_NEED) return;
  const int*   seq   = (const int*)d_in[0];
  const float* h0    = (const float*)d_in[1];
  const float* c0    = (const float*)d_in[2];
  const float* emb   = (const float*)d_in[3];
  const float* kern  = (const float*)d_in[4];
  const float* rkern = (const float*)d_in[5];
  const float* bias  = (const float*)d_in[6];
  float* out = (float*)d_out;

  hipFuncSetAttribute((const void*)lstm_enc,
                      hipFuncAttributeMaxDynamicSharedMemorySize, SMEM_BYTES);
  hipMemsetAsync(d_ws, 0, 4096, stream);  // zero barrier flags
  lstm_enc<<<dim3(256), dim3(128), SMEM_BYTES, stream>>>(
      seq, h0, c0, emb, kern, rkern, bias, out, (char*)d_ws);
}